// Round 14
// baseline (242.856 us; speedup 1.0000x reference)
//
#include <hip/hip_runtime.h>

#define G_N    32
#define MUL    128
#define RADII  20
#define CH     4
#define RES_B  180
#define RES_A  359
#define IDIM   36
#define COEFF_N (G_N*CH*RADII*IDIM)   // 92160 = 360*256
#define NQ     5                      // alpha chunks per (g,r)
#define PW     36                     // alpha-pairs per chunk (5*36 = 180)

typedef float v2f __attribute__((ext_vector_type(2)));

__device__ __forceinline__ float fexp2(float x){
#if __has_builtin(__builtin_amdgcn_exp2f)
  return __builtin_amdgcn_exp2f(x);
#else
  return exp2f(x);
#endif
}
__device__ __forceinline__ float flog2(float x){
#if __has_builtin(__builtin_amdgcn_logf)
  return __builtin_amdgcn_logf(x);
#else
  return log2f(x);
#endif
}
__device__ __forceinline__ unsigned enc_f(float f){
  unsigned u = __float_as_uint(f);
  return (u & 0x80000000u) ? ~u : (u | 0x80000000u);
}
__device__ __forceinline__ float dec_f(unsigned k){
  return __uint_as_float((k & 0x80000000u) ? (k ^ 0x80000000u) : ~k);
}

// Blocks 0..359: position_coeffs. Block 360: Gauss-Legendre nodes + normalized
// Legendre (pre-scaled by log2e) -> PYs. No Fourier table: compute kernels
// generate cos/sin by in-register rotation.
__global__ __launch_bounds__(256) void fused_prep_kernel(
                              const float* __restrict__ focus, const float* __restrict__ embt,
                              const float* __restrict__ W, const int* __restrict__ tspec,
                              float* __restrict__ out, float* __restrict__ PYs){
  __shared__ double ak[RES_B + 1], bk[RES_B + 1];
  int blk = blockIdx.x;
  int t   = threadIdx.x;
  if (blk == 360){
    const double PI = 3.14159265358979323846;
    const double LOG2E = 1.4426950408889634074;
    if (t >= 2 && t <= RES_B){
      ak[t] = (2.0*t - 1.0) / (double)t;
      bk[t] = (t - 1.0) / (double)t;
    }
    __syncthreads();
    if (t < RES_B){
      int i = RES_B - 1 - t;                     // numpy leggauss: ascending nodes
      double x = cos(PI * (i + 0.75) / (RES_B + 0.5));
      for (int it = 0; it < 3; ++it){            // Newton on P_180
        double p0 = 1.0, p1 = x;
        for (int k = 2; k <= RES_B; ++k){
          double t1 = ak[k] * x;
          double pk = fma(t1, p1, -(bk[k] * p0));
          p0 = p1; p1 = pk;
        }
        x -= p1 * (x*x - 1.0) / ((double)RES_B * (x*p1 - p0));
      }
      double y = x;
      double sy = sqrt(fmax(1.0 - y*y, 0.0));
      double P[6][6];
      P[0][0] = 1.0;
      for (int m = 1; m < 6; ++m) P[m][m] = (2.0*m - 1.0)*sy*P[m-1][m-1];
      for (int m = 0; m < 5; ++m) P[m+1][m] = (2.0*m + 1.0)*y*P[m][m];
      for (int m = 0; m < 6; ++m)
        for (int l = m + 2; l < 6; ++l)
          P[l][m] = ((2.0*l - 1.0)*y*P[l-1][m] - (l + m - 1.0)*P[l-2][m]) / (double)(l - m);
      const double fact[11] = {1,1,2,6,24,120,720,5040,40320,362880,3628800};
      for (int l = 0; l < 6; ++l)
        for (int m = 0; m <= l; ++m){
          double K = sqrt((2.0*l + 1.0)/(4.0*PI)*fact[l-m]/fact[l+m]);
          double v = K * P[l][m] * LOG2E;
          if (m > 0) v *= sqrt(2.0);
          PYs[t*36 + l*6 + m] = (float)v;
        }
    }
  } else {
    int idx = blk * 256 + t;        // < 92160 always
    int i36 = idx % IDIM;
    int go  = idx / IDIM;
    int o   = go % (CH*RADII);
    int g   = go / (CH*RADII);
    int l   = (int)sqrtf((float)i36 + 0.5f);
    int mo  = i36 - l*l;
    int dim = 2*l + 1;
    const float* fp = focus + g*(MUL*IDIM) + MUL*l*l + mo;
    const float* ep = embt + tspec[g]*(MUL*6) + MUL*l;
    const float* wp = W + l*(MUL*80) + o;
    float s = 0.f;
    #pragma unroll 4
    for (int i = 0; i < MUL; ++i)
      s = fmaf(fp[i*dim] * ep[i], wp[i*80], s);
    out[idx] = s * 0.088388347648318447f;  // 1/sqrt(128)
  }
}

// LANE = BETA. Block = (g, r, alpha-chunk q), 192 threads (3 waves; tid = beta,
// 12 idle). Per lane: tmp[44] PRIVATE in VGPRs (Legendre contraction once) =>
// the hot alpha-loop touches NO LDS/SMEM/global for operands. cos/sin(m*alpha)
// advance by in-register rotation (drift ~1e-5 over 36 steps, margin 0.16).
// Spill-safe rewrite of R11: no lambdas, no sincosf (pointer out-args), all
// indices compile-time, #pragma unroll 1 on alpha loop.
// WRITE=0: per-graph max of sp/sm -> atomicMax (no stores at all).
// WRITE=1: stage 16-col tiles in per-wave-PRIVATE LDS (same-wave DS ordering,
// no barriers), flush line-coalesced; logits = fma(log2(s), ln2, nsub).
template<int WRITE>
__global__ __launch_bounds__(192, 4) void compute_kernel(const float* __restrict__ coeffs,
                          const float* __restrict__ PYs,
                          float* __restrict__ out, unsigned* __restrict__ gmax){
  const float LN2 = 0.69314718055994531f;
  int blk = blockIdx.x;
  int q   = blk % NQ;
  int gr  = blk / NQ;                 // g*RADII + r
  int r   = gr % RADII;
  int g   = gr / RADII;
  int tid = threadIdx.x;
  int wave = tid >> 6, lane = tid & 63;
  bool valid = tid < RES_B;
  int bc = valid ? tid : (RES_B - 1);

  extern __shared__ float smem[];
  float* cv   = smem;                 // [4*36]
  float* wred = smem + 144;           // [4]
  float* tile = smem + 148;           // WRITE: [3 waves][2][64][17]

  for (int v = tid; v < CH*IDIM; v += 192)
    cv[v] = coeffs[((g*CH + v/IDIM)*RADII + r)*IDIM + (v % IDIM)];
  __syncthreads();

  // per-lane Legendre row
  float pr[36];
  {
    const float4* p4 = reinterpret_cast<const float4*>(PYs + bc*36);
    #pragma unroll
    for (int j = 0; j < 9; ++j){
      float4 v = p4[j];
      pr[4*j] = v.x; pr[4*j+1] = v.y; pr[4*j+2] = v.z; pr[4*j+3] = v.w;
    }
  }
  // private tmp: tA = channels (0,1), tB = (2,3); mm: 0=m0, 1..5=cos, 6..10=sin
  v2f tA[11], tB[11];
  #pragma unroll
  for (int mm = 0; mm < 11; ++mm){
    const int am = (mm == 0) ? 0 : (mm <= 5 ? mm : mm - 5);
    const int ii = (mm <= 5) ? am : -am;
    float s0 = 0.f, s1 = 0.f, s2 = 0.f, s3 = 0.f;
    #pragma unroll
    for (int l = am; l < 6; ++l){
      float p = pr[l*6 + am];
      const int idx = l*l + l + ii;
      s0 = fmaf(cv[idx],       p, s0);
      s1 = fmaf(cv[36 + idx],  p, s1);
      s2 = fmaf(cv[72 + idx],  p, s2);
      s3 = fmaf(cv[108 + idx], p, s3);
    }
    tA[mm] = (v2f){s0, s1};
    tB[mm] = (v2f){s2, s3};
  }

  // trig state (no sincosf -- separate calls, no pointer out-args)
  const float dA = (float)(6.283185307179586476925286766559 / 359.0);
  float a0 = dA * (float)(q * PW);
  float cs[5], sn[5], rc[5], rs[5];
  #pragma unroll
  for (int m = 1; m <= 5; ++m){
    cs[m-1] = cosf((float)m * a0);
    sn[m-1] = sinf((float)m * a0);
    rc[m-1] = cosf((float)m * dA);
    rs[m-1] = sinf((float)m * dA);
  }

  float nsub = 0.f;
  if (WRITE) nsub = -flog2(dec_f(gmax[g])) * LN2;
  size_t obase = (size_t)gr * RES_B * RES_A;
  float* tsp = tile + wave*(2*64*17);
  float* tsm = tsp + 64*17;
  int p0 = q * PW;

  if (WRITE){
    int sb = 0;
    #pragma unroll 1
    for (int seg = 0; seg < 3; ++seg){
      const int segw = (seg == 2) ? 4 : 16;
      #pragma unroll 1
      for (int ti = 0; ti < segw; ++ti){
        v2f C0 = tA[0], C1 = tB[0];
        #pragma unroll
        for (int m = 0; m < 5; ++m){
          v2f f = {cs[m], cs[m]};
          C0 = __builtin_elementwise_fma(tA[m+1], f, C0);
          C1 = __builtin_elementwise_fma(tB[m+1], f, C1);
        }
        v2f S0, S1;
        { v2f f = {sn[0], sn[0]}; S0 = tA[6]*f; S1 = tB[6]*f; }
        #pragma unroll
        for (int m = 1; m < 5; ++m){
          v2f f = {sn[m], sn[m]};
          S0 = __builtin_elementwise_fma(tA[6+m], f, S0);
          S1 = __builtin_elementwise_fma(tB[6+m], f, S1);
        }
        #pragma unroll
        for (int m = 0; m < 5; ++m){
          float nc = fmaf(cs[m], rc[m], -(sn[m]*rs[m]));
          float ns = fmaf(sn[m], rc[m],   cs[m]*rs[m]);
          cs[m] = nc; sn[m] = ns;
        }
        v2f hp0 = C0 + S0, hp1 = C1 + S1;
        v2f hm0 = C0 - S0, hm1 = C1 - S1;
        float sp = (fexp2(hp0.x) + fexp2(hp0.y)) + (fexp2(hp1.x) + fexp2(hp1.y));
        float sm = (fexp2(hm0.x) + fexp2(hm0.y)) + (fexp2(hm1.x) + fexp2(hm1.y));
        tsp[lane*17 + ti] = fmaf(flog2(sp), LN2, nsub);
        tsm[lane*17 + ti] = fmaf(flog2(sm), LN2, nsub);
      }
      // flush (per-wave-private tile: same-wave DS ops are ordered, no barrier)
      if (segw == 16){
        int c = lane & 15, rl = lane >> 4;
        #pragma unroll 1
        for (int rb = 0; rb < 64; rb += 4){
          int row = rb + rl;
          int b2 = wave*64 + row;
          if (b2 < RES_B){
            size_t rowb = obase + (size_t)b2 * RES_A;
            int pg = p0 + sb + c;
            out[rowb + pg] = tsp[row*17 + c];
            if (pg) out[rowb + (RES_A - pg)] = tsm[row*17 + c];
          }
        }
      } else {
        int c = lane & 3, rl = lane >> 2;
        #pragma unroll 1
        for (int rb = 0; rb < 64; rb += 16){
          int row = rb + rl;
          int b2 = wave*64 + row;
          if (b2 < RES_B){
            size_t rowb = obase + (size_t)b2 * RES_A;
            int pg = p0 + sb + c;
            out[rowb + pg] = tsp[row*17 + c];
            if (pg) out[rowb + (RES_A - pg)] = tsm[row*17 + c];
          }
        }
      }
      sb += segw;
    }
  } else {
    float mx = 0.f;
    #pragma unroll 1
    for (int ti = 0; ti < PW; ++ti){
      v2f C0 = tA[0], C1 = tB[0];
      #pragma unroll
      for (int m = 0; m < 5; ++m){
        v2f f = {cs[m], cs[m]};
        C0 = __builtin_elementwise_fma(tA[m+1], f, C0);
        C1 = __builtin_elementwise_fma(tB[m+1], f, C1);
      }
      v2f S0, S1;
      { v2f f = {sn[0], sn[0]}; S0 = tA[6]*f; S1 = tB[6]*f; }
      #pragma unroll
      for (int m = 1; m < 5; ++m){
        v2f f = {sn[m], sn[m]};
        S0 = __builtin_elementwise_fma(tA[6+m], f, S0);
        S1 = __builtin_elementwise_fma(tB[6+m], f, S1);
      }
      #pragma unroll
      for (int m = 0; m < 5; ++m){
        float nc = fmaf(cs[m], rc[m], -(sn[m]*rs[m]));
        float ns = fmaf(sn[m], rc[m],   cs[m]*rs[m]);
        cs[m] = nc; sn[m] = ns;
      }
      v2f hp0 = C0 + S0, hp1 = C1 + S1;
      v2f hm0 = C0 - S0, hm1 = C1 - S1;
      float sp = (fexp2(hp0.x) + fexp2(hp0.y)) + (fexp2(hp1.x) + fexp2(hp1.y));
      float sm = (fexp2(hm0.x) + fexp2(hm0.y)) + (fexp2(hm1.x) + fexp2(hm1.y));
      mx = fmaxf(mx, valid ? fmaxf(sp, sm) : 0.f);
    }
    #pragma unroll
    for (int off = 32; off > 0; off >>= 1)
      mx = fmaxf(mx, __shfl_xor(mx, off, 64));
    if (lane == 0) wred[wave] = mx;
    __syncthreads();
    if (tid == 0){
      float m = fmaxf(fmaxf(wred[0], wred[1]), wred[2]);
      atomicMax(gmax + g, enc_f(m));
    }
  }
}

extern "C" void kernel_launch(void* const* d_in, const int* in_sizes, int n_in,
                              void* d_out, int out_size, void* d_ws, size_t ws_size,
                              hipStream_t stream){
  const float* focus = (const float*)d_in[0];
  const float* embt  = (const float*)d_in[1];
  const float* W     = (const float*)d_in[2];
  const int*   tspec = (const int*)d_in[3];
  float* out = (float*)d_out;
  float* ws  = (float*)d_ws;
  unsigned* gmax = (unsigned*)d_ws;          // 32 slots (128 B)
  float* PYs  = ws + 32;                     // [180][36], 16B-aligned

  hipMemsetAsync(d_ws, 0, 128, stream);      // enc(sp>0) > 0, so 0 is identity
  fused_prep_kernel<<<361, 256, 0, stream>>>(focus, embt, W, tspec, out, PYs);
  float* logits = out + COEFF_N;
  size_t lds0 = 152 * sizeof(float);
  size_t lds1 = (148 + 3*2*64*17) * sizeof(float);
  compute_kernel<0><<<G_N*RADII*NQ, 192, lds0, stream>>>(out, PYs, logits, gmax);
  compute_kernel<1><<<G_N*RADII*NQ, 192, lds1, stream>>>(out, PYs, logits, gmax);
}

// Round 15
// 200.051 us; speedup vs baseline: 1.2140x; 1.2140x over previous
//
#include <hip/hip_runtime.h>

#define G_N    32
#define MUL    128
#define RADII  20
#define CH     4
#define RES_B  180
#define RES_A  359
#define IDIM   36
#define COEFF_N (G_N*CH*RADII*IDIM)   // 92160 = 360*256
#define NQ     5                      // alpha chunks
#define PW     36                     // alpha-pairs per chunk

typedef float v2f __attribute__((ext_vector_type(2)));

__device__ __forceinline__ float fexp2(float x){
#if __has_builtin(__builtin_amdgcn_exp2f)
  return __builtin_amdgcn_exp2f(x);
#else
  return exp2f(x);
#endif
}
__device__ __forceinline__ float flog2(float x){
#if __has_builtin(__builtin_amdgcn_logf)
  return __builtin_amdgcn_logf(x);
#else
  return log2f(x);
#endif
}
__device__ __forceinline__ unsigned enc_f(float f){
  unsigned u = __float_as_uint(f);
  return (u & 0x80000000u) ? ~u : (u | 0x80000000u);
}
__device__ __forceinline__ float dec_f(unsigned k){
  return __uint_as_float((k & 0x80000000u) ? (k ^ 0x80000000u) : ~k);
}

// Blocks 0..359: position_coeffs. Block 360: Gauss-Legendre + normalized
// Legendre (pre-scaled by log2e) -> PYs, plus the 12-float trig-init table:
// trig[q*2..] = cos/sin(dA*36*q), trig[10..11] = cos/sin(dA).
__global__ __launch_bounds__(256) void fused_prep_kernel(
                              const float* __restrict__ focus, const float* __restrict__ embt,
                              const float* __restrict__ W, const int* __restrict__ tspec,
                              float* __restrict__ out, float* __restrict__ PYs,
                              float* __restrict__ trig){
  __shared__ double ak[RES_B + 1], bk[RES_B + 1];
  int blk = blockIdx.x;
  int t   = threadIdx.x;
  if (blk == 360){
    const double PI = 3.14159265358979323846;
    const double LOG2E = 1.4426950408889634074;
    if (t >= 2 && t <= RES_B){
      ak[t] = (2.0*t - 1.0) / (double)t;
      bk[t] = (t - 1.0) / (double)t;
    }
    __syncthreads();
    if (t < RES_B){
      int i = RES_B - 1 - t;                     // numpy leggauss: ascending nodes
      double x = cos(PI * (i + 0.75) / (RES_B + 0.5));
      for (int it = 0; it < 3; ++it){            // Newton on P_180
        double p0 = 1.0, p1 = x;
        for (int k = 2; k <= RES_B; ++k){
          double t1 = ak[k] * x;
          double pk = fma(t1, p1, -(bk[k] * p0));
          p0 = p1; p1 = pk;
        }
        x -= p1 * (x*x - 1.0) / ((double)RES_B * (x*p1 - p0));
      }
      double y = x;
      double sy = sqrt(fmax(1.0 - y*y, 0.0));
      double P[6][6];
      P[0][0] = 1.0;
      for (int m = 1; m < 6; ++m) P[m][m] = (2.0*m - 1.0)*sy*P[m-1][m-1];
      for (int m = 0; m < 5; ++m) P[m+1][m] = (2.0*m + 1.0)*y*P[m][m];
      for (int m = 0; m < 6; ++m)
        for (int l = m + 2; l < 6; ++l)
          P[l][m] = ((2.0*l - 1.0)*y*P[l-1][m] - (l + m - 1.0)*P[l-2][m]) / (double)(l - m);
      const double fact[11] = {1,1,2,6,24,120,720,5040,40320,362880,3628800};
      for (int l = 0; l < 6; ++l)
        for (int m = 0; m <= l; ++m){
          double K = sqrt((2.0*l + 1.0)/(4.0*PI)*fact[l-m]/fact[l+m]);
          double v = K * P[l][m] * LOG2E;
          if (m > 0) v *= sqrt(2.0);
          PYs[t*36 + l*6 + m] = (float)v;
        }
    } else if (t < RES_B + 6){
      const double dA = 2.0*PI/359.0;
      int i = t - RES_B;
      if (i < 5){
        trig[i*2]     = (float)cos(dA*36.0*i);
        trig[i*2 + 1] = (float)sin(dA*36.0*i);
      } else {
        trig[10] = (float)cos(dA);
        trig[11] = (float)sin(dA);
      }
    }
  } else {
    int idx = blk * 256 + t;        // < 92160 always
    int i36 = idx % IDIM;
    int go  = idx / IDIM;
    int o   = go % (CH*RADII);
    int g   = go / (CH*RADII);
    int l   = (int)sqrtf((float)i36 + 0.5f);
    int mo  = i36 - l*l;
    int dim = 2*l + 1;
    const float* fp = focus + g*(MUL*IDIM) + MUL*l*l + mo;
    const float* ep = embt + tspec[g]*(MUL*6) + MUL*l;
    const float* wp = W + l*(MUL*80) + o;
    float s = 0.f;
    #pragma unroll 4
    for (int i = 0; i < MUL; ++i)
      s = fmaf(fp[i*dim] * ep[i], wp[i*80], s);
    out[idx] = s * 0.088388347648318447f;  // 1/sqrt(128)
  }
}

// Per-lane Legendre contraction for one Fourier mode (compile-time am, ii),
// for this lane's TWO channels (cvb points at channel-pair base in LDS).
template<int AM, int II>
__device__ __forceinline__ v2f contract2(const float* cvb, const float* pr){
  float a = 0.f, b = 0.f;
  #pragma unroll
  for (int l = AM; l < 6; ++l){
    float p = pr[l*6 + AM];
    a = fmaf(cvb[l*l + l + II],      p, a);
    b = fmaf(cvb[36 + l*l + l + II], p, b);
  }
  return (v2f){a, b};
}

// LANE = (beta, channel-half). Block = (gr, beta-half, alpha-chunk q), 192 thr.
// lane&31 -> beta offset, lane>>5 -> channel pair (0:ch01, 1:ch23). Each lane
// holds tA0..tA5 (cos modes) + tB1..tB5 (sin modes) = 22 VGPRs; trig state 4
// VGPRs (c1,s1 + rotation consts; m=2..5 derived by angle addition per iter).
// Working set ~55 regs -> fits the compiler's 64-VGPR budget WITHOUT spills
// (R11/R14 failure mode). Hot loop: no LDS/global operand traffic; one
// __shfl_xor(.,32) merges the 4-channel exp-sum across the lane pair.
// WRITE=0: per-graph max of tp/tm -> atomicMax. WRITE=1: half0 stores +alpha
// logits, half1 the mirror, via per-wave LDS tile + coalesced flush.
#define BODY(EMIT)                                                      \
  {                                                                     \
    float c2 = fmaf(c1, c1, -(s1*s1));                                  \
    float s2 = 2.f*c1*s1;                                               \
    float c3 = fmaf(c2, c1, -(s2*s1));                                  \
    float s3 = fmaf(s2, c1, c2*s1);                                     \
    float c4 = fmaf(c2, c2, -(s2*s2));                                  \
    float s4 = 2.f*c2*s2;                                               \
    float c5 = fmaf(c3, c2, -(s3*s2));                                  \
    float s5 = fmaf(s3, c2, c3*s2);                                     \
    v2f C = tA0;                                                        \
    C = __builtin_elementwise_fma(tA1, (v2f){c1,c1}, C);                \
    C = __builtin_elementwise_fma(tA2, (v2f){c2,c2}, C);                \
    C = __builtin_elementwise_fma(tA3, (v2f){c3,c3}, C);                \
    C = __builtin_elementwise_fma(tA4, (v2f){c4,c4}, C);                \
    C = __builtin_elementwise_fma(tA5, (v2f){c5,c5}, C);                \
    v2f S = tB1 * (v2f){s1,s1};                                         \
    S = __builtin_elementwise_fma(tB2, (v2f){s2,s2}, S);                \
    S = __builtin_elementwise_fma(tB3, (v2f){s3,s3}, S);                \
    S = __builtin_elementwise_fma(tB4, (v2f){s4,s4}, S);                \
    S = __builtin_elementwise_fma(tB5, (v2f){s5,s5}, S);                \
    v2f hp = C + S, hm = C - S;                                         \
    float pp_ = fexp2(hp.x) + fexp2(hp.y);                              \
    float pm_ = fexp2(hm.x) + fexp2(hm.y);                              \
    float send = half ? pp_ : pm_;                                      \
    float recv = __shfl_xor(send, 32, 64);                              \
    float tot  = half ? (pm_ + recv) : (pp_ + recv);                    \
    EMIT                                                                \
    float nc = fmaf(c1, rc1, -(s1*rs1));                                \
    float ns = fmaf(s1, rc1, c1*rs1);                                   \
    c1 = nc; s1 = ns;                                                   \
  }

template<int WRITE>
__global__ __launch_bounds__(192, 4) void compute_kernel(const float* __restrict__ coeffs,
                          const float* __restrict__ PYs, const float* __restrict__ trig,
                          float* __restrict__ out, unsigned* __restrict__ gmax){
  const float LN2 = 0.69314718055994531f;
  int blk = blockIdx.x;
  int q   = blk % NQ;
  int bh  = (blk / NQ) & 1;
  int gr  = blk / (NQ*2);             // g*RADII + r
  int g   = gr / RADII, r = gr % RADII;
  int tid = threadIdx.x;
  int wave = tid >> 6, lane = tid & 63;
  int half = lane >> 5, bl = lane & 31;
  int beta = bh*96 + wave*32 + bl;
  int bc   = (beta < RES_B) ? beta : (RES_B - 1);

  __shared__ float cv[144];
  __shared__ float wred[4];
  __shared__ float tile[WRITE ? 3*2*32*17 : 1];

  for (int v = tid; v < 144; v += 192)
    cv[v] = coeffs[((g*CH + v/36)*RADII + r)*36 + (v % 36)];
  __syncthreads();

  float pr[36];
  {
    const float4* p4 = reinterpret_cast<const float4*>(PYs + bc*36);
    #pragma unroll
    for (int j = 0; j < 9; ++j){
      float4 v = p4[j];
      pr[4*j] = v.x; pr[4*j+1] = v.y; pr[4*j+2] = v.z; pr[4*j+3] = v.w;
    }
  }
  const float* cvb = cv + half*72;
  v2f tA0 = contract2<0, 0>(cvb, pr);
  v2f tA1 = contract2<1, 1>(cvb, pr);
  v2f tA2 = contract2<2, 2>(cvb, pr);
  v2f tA3 = contract2<3, 3>(cvb, pr);
  v2f tA4 = contract2<4, 4>(cvb, pr);
  v2f tA5 = contract2<5, 5>(cvb, pr);
  v2f tB1 = contract2<1,-1>(cvb, pr);
  v2f tB2 = contract2<2,-2>(cvb, pr);
  v2f tB3 = contract2<3,-3>(cvb, pr);
  v2f tB4 = contract2<4,-4>(cvb, pr);
  v2f tB5 = contract2<5,-5>(cvb, pr);

  float c1 = trig[q*2], s1 = trig[q*2 + 1];
  float rc1 = trig[10], rs1 = trig[11];

  if (WRITE){
    float nsub = -flog2(dec_f(gmax[g])) * LN2;
    float* tw = tile + wave*(2*32*17);
    int sb = 0;
    #pragma unroll 1
    for (int seg = 0; seg < 3; ++seg){
      int segw = (seg == 2) ? 4 : 16;
      #pragma unroll 1
      for (int ti = 0; ti < segw; ++ti)
        BODY( tw[half*(32*17) + bl*17 + ti] = fmaf(flog2(tot), LN2, nsub); )
      // flush per-wave tile (same-wave DS ordering; no barrier needed)
      int c = lane & 15, rl = lane >> 4;
      #pragma unroll 1
      for (int rb = 0; rb < 32; rb += 4){
        int row = rb + rl;
        int b2 = bh*96 + wave*32 + row;
        if (b2 < RES_B && c < segw){
          size_t ro = ((size_t)gr*RES_B + b2)*RES_A;
          int pg = q*PW + sb + c;
          out[ro + pg] = tw[row*17 + c];
          if (pg) out[ro + (RES_A - pg)] = tw[32*17 + row*17 + c];
        }
      }
      sb += segw;
    }
  } else {
    float mx = 0.f;
    #pragma unroll 1
    for (int ti = 0; ti < PW; ++ti)
      BODY( mx = fmaxf(mx, tot); )
    // clamped-beta lanes duplicate beta=179's true values: harmless in a max
    #pragma unroll
    for (int off = 32; off > 0; off >>= 1)
      mx = fmaxf(mx, __shfl_xor(mx, off, 64));
    if (lane == 0) wred[wave] = mx;
    __syncthreads();
    if (tid == 0){
      float m = fmaxf(fmaxf(wred[0], wred[1]), wred[2]);
      atomicMax(gmax + g, enc_f(m));
    }
  }
}

extern "C" void kernel_launch(void* const* d_in, const int* in_sizes, int n_in,
                              void* d_out, int out_size, void* d_ws, size_t ws_size,
                              hipStream_t stream){
  const float* focus = (const float*)d_in[0];
  const float* embt  = (const float*)d_in[1];
  const float* W     = (const float*)d_in[2];
  const int*   tspec = (const int*)d_in[3];
  float* out = (float*)d_out;
  float* ws  = (float*)d_ws;
  unsigned* gmax = (unsigned*)d_ws;          // 32 slots (128 B)
  float* PYs  = ws + 32;                     // [180][36], 16B-aligned
  float* trig = ws + 32 + RES_B*36;          // 12 floats

  hipMemsetAsync(d_ws, 0, 128, stream);      // enc(x>0) > 0, so 0 is identity
  fused_prep_kernel<<<361, 256, 0, stream>>>(focus, embt, W, tspec, out, PYs, trig);
  float* logits = out + COEFF_N;
  compute_kernel<0><<<G_N*RADII*2*NQ, 192, 0, stream>>>(out, PYs, trig, logits, gmax);
  compute_kernel<1><<<G_N*RADII*2*NQ, 192, 0, stream>>>(out, PYs, trig, logits, gmax);
}

// Round 16
// 145.709 us; speedup vs baseline: 1.6667x; 1.3729x over previous
//
#include <hip/hip_runtime.h>

#define G_N    32
#define MUL    128
#define RADII  20
#define CH     4
#define RES_B  180
#define RES_A  359
#define IDIM   36
#define COEFF_N (G_N*CH*RADII*IDIM)   // 92160 = 360*256
#define NCHUNK 5
#define BCH_BLK 36                    // betas per block (4 waves)
#define BCH_W   9                     // betas per wave
#define PER_G   (RADII*RES_B*RES_A)   // 1292400
#define TOT_L   (G_N*PER_G)           // 41356800 logits

typedef float v2f __attribute__((ext_vector_type(2)));

__device__ __forceinline__ float fexp2(float x){
#if __has_builtin(__builtin_amdgcn_exp2f)
  return __builtin_amdgcn_exp2f(x);
#else
  return exp2f(x);
#endif
}
__device__ __forceinline__ float flog2(float x){
#if __has_builtin(__builtin_amdgcn_logf)
  return __builtin_amdgcn_logf(x);
#else
  return log2f(x);
#endif
}
__device__ __forceinline__ unsigned enc_f(float f){
  unsigned u = __float_as_uint(f);
  return (u & 0x80000000u) ? ~u : (u | 0x80000000u);
}
__device__ __forceinline__ float dec_f(unsigned k){
  return __uint_as_float((k & 0x80000000u) ? (k ^ 0x80000000u) : ~k);
}

// Blocks 0..359: position_coeffs. Block 360: Gauss-Legendre + Legendre*log2e
// -> PYs; Fourier rows -> Ftab.
__global__ __launch_bounds__(256) void fused_prep_kernel(
                              const float* __restrict__ focus, const float* __restrict__ embt,
                              const float* __restrict__ W, const int* __restrict__ tspec,
                              float* __restrict__ out,
                              float* __restrict__ PYs, float* __restrict__ Ftab){
  __shared__ double ak[RES_B + 1], bk[RES_B + 1];
  int blk = blockIdx.x;
  int t   = threadIdx.x;
  if (blk == 360){
    const double PI = 3.14159265358979323846;
    const double LOG2E = 1.4426950408889634074;
    if (t >= 2 && t <= RES_B){
      ak[t] = (2.0*t - 1.0) / (double)t;
      bk[t] = (t - 1.0) / (double)t;
    }
    __syncthreads();
    if (t < RES_B){
      int i = RES_B - 1 - t;
      double x = cos(PI * (i + 0.75) / (RES_B + 0.5));
      for (int it = 0; it < 3; ++it){
        double p0 = 1.0, p1 = x;
        for (int k = 2; k <= RES_B; ++k){
          double t1 = ak[k] * x;
          double pk = fma(t1, p1, -(bk[k] * p0));
          p0 = p1; p1 = pk;
        }
        x -= p1 * (x*x - 1.0) / ((double)RES_B * (x*p1 - p0));
      }
      double y = x;
      double sy = sqrt(fmax(1.0 - y*y, 0.0));
      double P[6][6];
      P[0][0] = 1.0;
      for (int m = 1; m < 6; ++m) P[m][m] = (2.0*m - 1.0)*sy*P[m-1][m-1];
      for (int m = 0; m < 5; ++m) P[m+1][m] = (2.0*m + 1.0)*y*P[m][m];
      for (int m = 0; m < 6; ++m)
        for (int l = m + 2; l < 6; ++l)
          P[l][m] = ((2.0*l - 1.0)*y*P[l-1][m] - (l + m - 1.0)*P[l-2][m]) / (double)(l - m);
      const double fact[11] = {1,1,2,6,24,120,720,5040,40320,362880,3628800};
      for (int l = 0; l < 6; ++l)
        for (int m = 0; m <= l; ++m){
          double K = sqrt((2.0*l + 1.0)/(4.0*PI)*fact[l-m]/fact[l+m]);
          double v = K * P[l][m] * LOG2E;
          if (m > 0) v *= sqrt(2.0);
          PYs[t*36 + l*6 + m] = (float)v;
        }
    }
    for (int a = t; a < RES_A; a += 256){
      double al = 2.0*PI*a/(double)RES_A;
      Ftab[a*12 + 0] = 1.0f;
      for (int m = 1; m <= 5; ++m){
        Ftab[a*12 + m]     = (float)cos(m*al);
        Ftab[a*12 + 5 + m] = (float)sin(m*al);
      }
      Ftab[a*12 + 11] = 0.f;
    }
  } else {
    int idx = blk * 256 + t;
    int i36 = idx % IDIM;
    int go  = idx / IDIM;
    int o   = go % (CH*RADII);
    int g   = go / (CH*RADII);
    int l   = (int)sqrtf((float)i36 + 0.5f);
    int mo  = i36 - l*l;
    int dim = 2*l + 1;
    const float* fp = focus + g*(MUL*IDIM) + MUL*l*l + mo;
    const float* ep = embt + tspec[g]*(MUL*6) + MUL*l;
    const float* wp = W + l*(MUL*80) + o;
    float s = 0.f;
    #pragma unroll 4
    for (int i = 0; i < MUL; ++i)
      s = fmaf(fp[i*dim] * ep[i], wp[i*80], s);
    out[idx] = s * 0.088388347648318447f;  // 1/sqrt(128)
  }
}

// R13's mm-major compute, single pass: computes h = log2(sum_c 2^{h_c}) for
// the alpha-pair (p, 359-p), stores h (fp16 if HALF else fp32) and tracks the
// per-graph max of h via atomicMax (log2-domain). fixup applies ln2*(h-hmax).
template<int HALF>
__global__ __launch_bounds__(256, 4) void compute_kernel(const float* __restrict__ coeffs,
                          const float* __restrict__ PYs, const float* __restrict__ Ftab,
                          _Float16* __restrict__ hbuf, float* __restrict__ fbuf,
                          unsigned* __restrict__ gmax){
  int blk   = blockIdx.x;
  int chunk = blk % NCHUNK;
  int gr    = blk / NCHUNK;
  int r = gr % RADII;
  int g = gr / RADII;
  int tid  = threadIdx.x;
  int wave = tid >> 6, lane = tid & 63;
  int b0   = chunk * BCH_BLK;

  __shared__ float cv[CH][IDIM];
  __shared__ __align__(16) float tmpa[BCH_BLK][12][4];
  __shared__ float wred[4];

  for (int v = tid; v < CH*IDIM; v += 256){
    int c = v / IDIM, i = v % IDIM;
    cv[c][i] = coeffs[((g*CH + c)*RADII + r)*IDIM + i];
  }
  float f0[11], f1[11], f2[11];
  {
    const float4* Fq = reinterpret_cast<const float4*>(Ftab);
    float4 a0 = Fq[lane*3],       a1 = Fq[lane*3+1],       a2 = Fq[lane*3+2];
    float4 b0v = Fq[(lane+64)*3], b1 = Fq[(lane+64)*3+1],  b2 = Fq[(lane+64)*3+2];
    float4 c0 = Fq[(lane+128)*3], c1 = Fq[(lane+128)*3+1], c2 = Fq[(lane+128)*3+2];
    f0[0]=a0.x; f0[1]=a0.y; f0[2]=a0.z; f0[3]=a0.w; f0[4]=a1.x; f0[5]=a1.y;
    f0[6]=a1.z; f0[7]=a1.w; f0[8]=a2.x; f0[9]=a2.y; f0[10]=a2.z;
    f1[0]=b0v.x; f1[1]=b0v.y; f1[2]=b0v.z; f1[3]=b0v.w; f1[4]=b1.x; f1[5]=b1.y;
    f1[6]=b1.z; f1[7]=b1.w; f1[8]=b2.x; f1[9]=b2.y; f1[10]=b2.z;
    f2[0]=c0.x; f2[1]=c0.y; f2[2]=c0.z; f2[3]=c0.w; f2[4]=c1.x; f2[5]=c1.y;
    f2[6]=c1.z; f2[7]=c1.w; f2[8]=c2.x; f2[9]=c2.y; f2[10]=c2.z;
  }
  __syncthreads();

  for (int v = tid; v < BCH_BLK*44; v += 256){
    int bl = v / 44, cm = v % 44;
    int c = cm / 11, mm = cm % 11;
    int am, ii;
    if (mm == 0)      { am = 0;      ii = 0;        }
    else if (mm <= 5) { am = mm;     ii = mm;       }
    else              { am = mm - 5; ii = -(mm-5);  }
    const float* py = PYs + (b0 + bl)*36 + am;
    float s = 0.f;
    for (int l = am; l < 6; ++l)
      s = fmaf(cv[c][l*l + l + ii], py[l*6], s);
    tmpa[bl][mm][c] = s;
  }
  __syncthreads();

  float smx[3] = {-1e30f, -1e30f, -1e30f};
  bool tail_ok = (lane < 52);
  size_t rowoff = ((size_t)gr*RES_B + b0 + wave*BCH_W)*RES_A;
  for (int bl = 0; bl < BCH_W; ++bl){
    const float4* tq = reinterpret_cast<const float4*>(&tmpa[wave*BCH_W + bl][0][0]);
    v2f C01[3], C23[3], S01[3], S23[3];
    {
      float4 qv = tq[0];
      v2f a = {qv.x, qv.y}, b = {qv.z, qv.w};
      #pragma unroll
      for (int k = 0; k < 3; ++k){ C01[k] = a; C23[k] = b; }
    }
    #pragma unroll
    for (int mm = 1; mm <= 5; ++mm){
      float4 qv = tq[mm];
      v2f a = {qv.x, qv.y}, b = {qv.z, qv.w};
      C01[0] = __builtin_elementwise_fma(a, (v2f){f0[mm], f0[mm]}, C01[0]);
      C23[0] = __builtin_elementwise_fma(b, (v2f){f0[mm], f0[mm]}, C23[0]);
      C01[1] = __builtin_elementwise_fma(a, (v2f){f1[mm], f1[mm]}, C01[1]);
      C23[1] = __builtin_elementwise_fma(b, (v2f){f1[mm], f1[mm]}, C23[1]);
      C01[2] = __builtin_elementwise_fma(a, (v2f){f2[mm], f2[mm]}, C01[2]);
      C23[2] = __builtin_elementwise_fma(b, (v2f){f2[mm], f2[mm]}, C23[2]);
    }
    {
      float4 qv = tq[6];
      v2f a = {qv.x, qv.y}, b = {qv.z, qv.w};
      S01[0] = a * (v2f){f0[6], f0[6]};  S23[0] = b * (v2f){f0[6], f0[6]};
      S01[1] = a * (v2f){f1[6], f1[6]};  S23[1] = b * (v2f){f1[6], f1[6]};
      S01[2] = a * (v2f){f2[6], f2[6]};  S23[2] = b * (v2f){f2[6], f2[6]};
    }
    #pragma unroll
    for (int mm = 7; mm <= 10; ++mm){
      float4 qv = tq[mm];
      v2f a = {qv.x, qv.y}, b = {qv.z, qv.w};
      S01[0] = __builtin_elementwise_fma(a, (v2f){f0[mm], f0[mm]}, S01[0]);
      S23[0] = __builtin_elementwise_fma(b, (v2f){f0[mm], f0[mm]}, S23[0]);
      S01[1] = __builtin_elementwise_fma(a, (v2f){f1[mm], f1[mm]}, S01[1]);
      S23[1] = __builtin_elementwise_fma(b, (v2f){f1[mm], f1[mm]}, S23[1]);
      S01[2] = __builtin_elementwise_fma(a, (v2f){f2[mm], f2[mm]}, S01[2]);
      S23[2] = __builtin_elementwise_fma(b, (v2f){f2[mm], f2[mm]}, S23[2]);
    }
    #pragma unroll
    for (int k = 0; k < 3; ++k){
      v2f hp0 = C01[k] + S01[k], hp1 = C23[k] + S23[k];
      v2f hm0 = C01[k] - S01[k], hm1 = C23[k] - S23[k];
      float sp = (fexp2(hp0.x) + fexp2(hp0.y)) + (fexp2(hp1.x) + fexp2(hp1.y));
      float sm = (fexp2(hm0.x) + fexp2(hm0.y)) + (fexp2(hm1.x) + fexp2(hm1.y));
      float hvp = flog2(sp), hvm = flog2(sm);
      smx[k] = fmaxf(smx[k], fmaxf(hvp, hvm));   // k2 tail: valid duplicates
      if (k < 2 || tail_ok){
        int p = lane + 64*k;
        if (HALF){
          hbuf[rowoff + p] = (_Float16)hvp;
          if (p) hbuf[rowoff + 359 - p] = (_Float16)hvm;
        } else {
          fbuf[rowoff + p] = hvp;
          if (p) fbuf[rowoff + 359 - p] = hvm;
        }
      }
    }
    rowoff += RES_A;
  }
  float smax = fmaxf(fmaxf(smx[0], smx[1]), smx[2]);
  #pragma unroll
  for (int off = 32; off > 0; off >>= 1)
    smax = fmaxf(smax, __shfl_xor(smax, off, 64));
  if (lane == 0) wred[wave] = smax;
  __syncthreads();
  if (tid == 0){
    float m = fmaxf(fmaxf(wred[0], wred[1]), fmaxf(wred[2], wred[3]));
    atomicMax(gmax + g, enc_f(m));             // max of h (log2-domain)
  }
}

// HALF=1: read 8 fp16 h, write 8 fp32 logits = ln2*(h - hmax). 249 MB total.
// HALF=0: in-place fp32 (R8 fallback). 332 MB total.
template<int HALF>
__global__ __launch_bounds__(256) void fixup_kernel(const _Float16* __restrict__ hbuf,
                                                    float* __restrict__ logits,
                                                    const unsigned* __restrict__ gmax){
  const float LN2 = 0.69314718055994531f;
  if (HALF){
    const int total8 = TOT_L/8;                 // 5169600
    const uint4* hv = reinterpret_cast<const uint4*>(hbuf);
    float4* l4 = reinterpret_cast<float4*>(logits);
    int stride = gridDim.x * 256;
    for (int i = blockIdx.x * 256 + threadIdx.x; i < total8; i += stride){
      int g = (int)(((unsigned)i) / (PER_G/8));
      float nsub = -dec_f(gmax[g]) * LN2;
      union { uint4 u; _Float16 h[8]; } un;
      un.u = hv[i];
      float4 o0, o1;
      o0.x = fmaf((float)un.h[0], LN2, nsub);
      o0.y = fmaf((float)un.h[1], LN2, nsub);
      o0.z = fmaf((float)un.h[2], LN2, nsub);
      o0.w = fmaf((float)un.h[3], LN2, nsub);
      o1.x = fmaf((float)un.h[4], LN2, nsub);
      o1.y = fmaf((float)un.h[5], LN2, nsub);
      o1.z = fmaf((float)un.h[6], LN2, nsub);
      o1.w = fmaf((float)un.h[7], LN2, nsub);
      l4[2*i]   = o0;
      l4[2*i+1] = o1;
    }
  } else {
    const int total4 = TOT_L/4;
    float4* l4 = reinterpret_cast<float4*>(logits);
    int stride = gridDim.x * 256;
    for (int i = blockIdx.x * 256 + threadIdx.x; i < total4; i += stride){
      int g = (int)(((unsigned)i) / (PER_G/4));
      float nsub = -dec_f(gmax[g]) * LN2;
      float4 v = l4[i];
      v.x = fmaf(v.x, LN2, nsub); v.y = fmaf(v.y, LN2, nsub);
      v.z = fmaf(v.z, LN2, nsub); v.w = fmaf(v.w, LN2, nsub);
      l4[i] = v;
    }
  }
}

extern "C" void kernel_launch(void* const* d_in, const int* in_sizes, int n_in,
                              void* d_out, int out_size, void* d_ws, size_t ws_size,
                              hipStream_t stream){
  const float* focus = (const float*)d_in[0];
  const float* embt  = (const float*)d_in[1];
  const float* W     = (const float*)d_in[2];
  const int*   tspec = (const int*)d_in[3];
  float* out = (float*)d_out;
  float* ws  = (float*)d_ws;
  unsigned* gmax = (unsigned*)d_ws;          // 32 u32
  float* PYs  = ws + 32;                     // [180][36]
  float* Ftab = ws + 32 + RES_B*36;          // [359][12]
  _Float16* hbuf = (_Float16*)(ws + 16384);  // 83 MB if available

  const size_t need = 16384*4 + (size_t)TOT_L*2;
  const bool use_half = (ws_size >= need);

  hipMemsetAsync(d_ws, 0, 128, stream);
  fused_prep_kernel<<<361, 256, 0, stream>>>(focus, embt, W, tspec, out, PYs, Ftab);
  float* logits = out + COEFF_N;
  if (use_half){
    compute_kernel<1><<<G_N*RADII*NCHUNK, 256, 0, stream>>>(out, PYs, Ftab, hbuf, logits, gmax);
    fixup_kernel<1><<<2048, 256, 0, stream>>>(hbuf, logits, gmax);
  } else {
    compute_kernel<0><<<G_N*RADII*NCHUNK, 256, 0, stream>>>(out, PYs, Ftab, hbuf, logits, gmax);
    fixup_kernel<0><<<2048, 256, 0, stream>>>(hbuf, logits, gmax);
  }
}

// Round 17
// 144.923 us; speedup vs baseline: 1.6758x; 1.0054x over previous
//
#include <hip/hip_runtime.h>

#define G_N    32
#define MUL    128
#define RADII  20
#define CH     4
#define RES_B  180
#define RES_A  359
#define IDIM   36
#define COEFF_N (G_N*CH*RADII*IDIM)   // 92160 = 360*256
#define NCHUNK 5
#define BCH_BLK 36                    // betas per block (4 waves)
#define BCH_W   9                     // betas per wave
#define PER_G   (RADII*RES_B*RES_A)   // 1292400
#define TOT_L   (G_N*PER_G)           // 41356800 logits
#define TMP_T   (G_N*RADII*RES_B)     // 115200 rows of [12][4] floats

typedef float v2f __attribute__((ext_vector_type(2)));

__device__ __forceinline__ float fexp2(float x){
#if __has_builtin(__builtin_amdgcn_exp2f)
  return __builtin_amdgcn_exp2f(x);
#else
  return exp2f(x);
#endif
}
__device__ __forceinline__ float flog2(float x){
#if __has_builtin(__builtin_amdgcn_logf)
  return __builtin_amdgcn_logf(x);
#else
  return log2f(x);
#endif
}
__device__ __forceinline__ unsigned enc_f(float f){
  unsigned u = __float_as_uint(f);
  return (u & 0x80000000u) ? ~u : (u | 0x80000000u);
}
__device__ __forceinline__ float dec_f(unsigned k){
  return __uint_as_float((k & 0x80000000u) ? (k ^ 0x80000000u) : ~k);
}

__global__ __launch_bounds__(256) void fused_prep_kernel(
                              const float* __restrict__ focus, const float* __restrict__ embt,
                              const float* __restrict__ W, const int* __restrict__ tspec,
                              float* __restrict__ out,
                              float* __restrict__ PYs, float* __restrict__ Ftab){
  __shared__ double ak[RES_B + 1], bk[RES_B + 1];
  int blk = blockIdx.x;
  int t   = threadIdx.x;
  if (blk == 360){
    const double PI = 3.14159265358979323846;
    const double LOG2E = 1.4426950408889634074;
    if (t >= 2 && t <= RES_B){
      ak[t] = (2.0*t - 1.0) / (double)t;
      bk[t] = (t - 1.0) / (double)t;
    }
    __syncthreads();
    if (t < RES_B){
      int i = RES_B - 1 - t;
      double x = cos(PI * (i + 0.75) / (RES_B + 0.5));
      for (int it = 0; it < 3; ++it){
        double p0 = 1.0, p1 = x;
        for (int k = 2; k <= RES_B; ++k){
          double t1 = ak[k] * x;
          double pk = fma(t1, p1, -(bk[k] * p0));
          p0 = p1; p1 = pk;
        }
        x -= p1 * (x*x - 1.0) / ((double)RES_B * (x*p1 - p0));
      }
      double y = x;
      double sy = sqrt(fmax(1.0 - y*y, 0.0));
      double P[6][6];
      P[0][0] = 1.0;
      for (int m = 1; m < 6; ++m) P[m][m] = (2.0*m - 1.0)*sy*P[m-1][m-1];
      for (int m = 0; m < 5; ++m) P[m+1][m] = (2.0*m + 1.0)*y*P[m][m];
      for (int m = 0; m < 6; ++m)
        for (int l = m + 2; l < 6; ++l)
          P[l][m] = ((2.0*l - 1.0)*y*P[l-1][m] - (l + m - 1.0)*P[l-2][m]) / (double)(l - m);
      const double fact[11] = {1,1,2,6,24,120,720,5040,40320,362880,3628800};
      for (int l = 0; l < 6; ++l)
        for (int m = 0; m <= l; ++m){
          double K = sqrt((2.0*l + 1.0)/(4.0*PI)*fact[l-m]/fact[l+m]);
          double v = K * P[l][m] * LOG2E;
          if (m > 0) v *= sqrt(2.0);
          PYs[t*36 + l*6 + m] = (float)v;
        }
    }
    for (int a = t; a < RES_A; a += 256){
      double al = 2.0*PI*a/(double)RES_A;
      Ftab[a*12 + 0] = 1.0f;
      for (int m = 1; m <= 5; ++m){
        Ftab[a*12 + m]     = (float)cos(m*al);
        Ftab[a*12 + 5 + m] = (float)sin(m*al);
      }
      Ftab[a*12 + 11] = 0.f;
    }
  } else {
    int idx = blk * 256 + t;
    int i36 = idx % IDIM;
    int go  = idx / IDIM;
    int o   = go % (CH*RADII);
    int g   = go / (CH*RADII);
    int l   = (int)sqrtf((float)i36 + 0.5f);
    int mo  = i36 - l*l;
    int dim = 2*l + 1;
    const float* fp = focus + g*(MUL*IDIM) + MUL*l*l + mo;
    const float* ep = embt + tspec[g]*(MUL*6) + MUL*l;
    const float* wp = W + l*(MUL*80) + o;
    float s = 0.f;
    #pragma unroll 4
    for (int i = 0; i < MUL; ++i)
      s = fmaf(fp[i*dim] * ep[i], wp[i*80], s);
    out[idx] = s * 0.088388347648318447f;  // 1/sqrt(128)
  }
}

// Hoisted phase-1: one thread per (t=gr*180+beta, mm), all 4 channels ->
// one coalesced float4 store into the padded [TMP_T][12][4] layout.
__global__ __launch_bounds__(256) void tmp_kernel(const float* __restrict__ coeffs,
                                                  const float* __restrict__ PYs,
                                                  float* __restrict__ tmpg){
  int idx  = blockIdx.x * 256 + threadIdx.x;   // < TMP_T*11 exactly
  int mm   = idx % 11;
  int t    = idx / 11;
  int beta = t % RES_B;
  int gr   = t / RES_B;
  int g = gr / RADII, r = gr % RADII;
  int am, ii;
  if (mm == 0)      { am = 0;      ii = 0;        }
  else if (mm <= 5) { am = mm;     ii = mm;       }
  else              { am = mm - 5; ii = -(mm-5);  }
  const float* py  = PYs + beta*36 + am;
  const float* cvp = coeffs + (size_t)(g*CH*RADII + r)*IDIM;   // channel 0
  float s0 = 0.f, s1 = 0.f, s2 = 0.f, s3 = 0.f;
  for (int l = am; l < 6; ++l){
    float p = py[l*6];
    int o = l*l + l + ii;
    s0 = fmaf(cvp[o],                p, s0);
    s1 = fmaf(cvp[RADII*IDIM + o],   p, s1);
    s2 = fmaf(cvp[2*RADII*IDIM + o], p, s2);
    s3 = fmaf(cvp[3*RADII*IDIM + o], p, s3);
  }
  float4 v = {s0, s1, s2, s3};
  reinterpret_cast<float4*>(tmpg)[t*12 + mm] = v;
}

template<int PRE, int HALF>
__global__ __launch_bounds__(256, 4) void compute_kernel(const float* __restrict__ coeffs,
                          const float* __restrict__ PYs, const float* __restrict__ Ftab,
                          const float* __restrict__ tmpg,
                          _Float16* __restrict__ hbuf, float* __restrict__ fbuf,
                          unsigned* __restrict__ gmax){
  int blk   = blockIdx.x;
  int chunk = blk % NCHUNK;
  int gr    = blk / NCHUNK;
  int r = gr % RADII;
  int g = gr / RADII;
  int tid  = threadIdx.x;
  int wave = tid >> 6, lane = tid & 63;
  int b0   = chunk * BCH_BLK;

  __shared__ float cv[CH][IDIM];
  __shared__ __align__(16) float tmpa[BCH_BLK][12][4];
  __shared__ float wred[4];

  if (PRE){
    const float4* src = reinterpret_cast<const float4*>(tmpg) + ((size_t)gr*RES_B + b0)*12;
    float4* dst = reinterpret_cast<float4*>(&tmpa[0][0][0]);
    dst[tid] = src[tid];                           // 0..255
    if (tid < 176) dst[256 + tid] = src[256 + tid];// 256..431 (36*12 = 432)
  } else {
    for (int v = tid; v < CH*IDIM; v += 256){
      int c = v / IDIM, i = v % IDIM;
      cv[c][i] = coeffs[((g*CH + c)*RADII + r)*IDIM + i];
    }
  }
  float f0[11], f1[11], f2[11];
  {
    const float4* Fq = reinterpret_cast<const float4*>(Ftab);
    float4 a0 = Fq[lane*3],       a1 = Fq[lane*3+1],       a2 = Fq[lane*3+2];
    float4 b0v = Fq[(lane+64)*3], b1 = Fq[(lane+64)*3+1],  b2 = Fq[(lane+64)*3+2];
    float4 c0 = Fq[(lane+128)*3], c1 = Fq[(lane+128)*3+1], c2 = Fq[(lane+128)*3+2];
    f0[0]=a0.x; f0[1]=a0.y; f0[2]=a0.z; f0[3]=a0.w; f0[4]=a1.x; f0[5]=a1.y;
    f0[6]=a1.z; f0[7]=a1.w; f0[8]=a2.x; f0[9]=a2.y; f0[10]=a2.z;
    f1[0]=b0v.x; f1[1]=b0v.y; f1[2]=b0v.z; f1[3]=b0v.w; f1[4]=b1.x; f1[5]=b1.y;
    f1[6]=b1.z; f1[7]=b1.w; f1[8]=b2.x; f1[9]=b2.y; f1[10]=b2.z;
    f2[0]=c0.x; f2[1]=c0.y; f2[2]=c0.z; f2[3]=c0.w; f2[4]=c1.x; f2[5]=c1.y;
    f2[6]=c1.z; f2[7]=c1.w; f2[8]=c2.x; f2[9]=c2.y; f2[10]=c2.z;
  }
  __syncthreads();

  if (!PRE){
    for (int v = tid; v < BCH_BLK*44; v += 256){
      int bl = v / 44, cm = v % 44;
      int c = cm / 11, mm = cm % 11;
      int am, ii;
      if (mm == 0)      { am = 0;      ii = 0;        }
      else if (mm <= 5) { am = mm;     ii = mm;       }
      else              { am = mm - 5; ii = -(mm-5);  }
      const float* py = PYs + (b0 + bl)*36 + am;
      float s = 0.f;
      for (int l = am; l < 6; ++l)
        s = fmaf(cv[c][l*l + l + ii], py[l*6], s);
      tmpa[bl][mm][c] = s;
    }
    __syncthreads();
  }

  float smx[3] = {-1e30f, -1e30f, -1e30f};
  bool tail_ok = (lane < 52);
  size_t rowoff = ((size_t)gr*RES_B + b0 + wave*BCH_W)*RES_A;
  for (int bl = 0; bl < BCH_W; ++bl){
    const float4* tq = reinterpret_cast<const float4*>(&tmpa[wave*BCH_W + bl][0][0]);
    v2f C01[3], C23[3], S01[3], S23[3];
    {
      float4 qv = tq[0];
      v2f a = {qv.x, qv.y}, b = {qv.z, qv.w};
      #pragma unroll
      for (int k = 0; k < 3; ++k){ C01[k] = a; C23[k] = b; }
    }
    #pragma unroll
    for (int mm = 1; mm <= 5; ++mm){
      float4 qv = tq[mm];
      v2f a = {qv.x, qv.y}, b = {qv.z, qv.w};
      C01[0] = __builtin_elementwise_fma(a, (v2f){f0[mm], f0[mm]}, C01[0]);
      C23[0] = __builtin_elementwise_fma(b, (v2f){f0[mm], f0[mm]}, C23[0]);
      C01[1] = __builtin_elementwise_fma(a, (v2f){f1[mm], f1[mm]}, C01[1]);
      C23[1] = __builtin_elementwise_fma(b, (v2f){f1[mm], f1[mm]}, C23[1]);
      C01[2] = __builtin_elementwise_fma(a, (v2f){f2[mm], f2[mm]}, C01[2]);
      C23[2] = __builtin_elementwise_fma(b, (v2f){f2[mm], f2[mm]}, C23[2]);
    }
    {
      float4 qv = tq[6];
      v2f a = {qv.x, qv.y}, b = {qv.z, qv.w};
      S01[0] = a * (v2f){f0[6], f0[6]};  S23[0] = b * (v2f){f0[6], f0[6]};
      S01[1] = a * (v2f){f1[6], f1[6]};  S23[1] = b * (v2f){f1[6], f1[6]};
      S01[2] = a * (v2f){f2[6], f2[6]};  S23[2] = b * (v2f){f2[6], f2[6]};
    }
    #pragma unroll
    for (int mm = 7; mm <= 10; ++mm){
      float4 qv = tq[mm];
      v2f a = {qv.x, qv.y}, b = {qv.z, qv.w};
      S01[0] = __builtin_elementwise_fma(a, (v2f){f0[mm], f0[mm]}, S01[0]);
      S23[0] = __builtin_elementwise_fma(b, (v2f){f0[mm], f0[mm]}, S23[0]);
      S01[1] = __builtin_elementwise_fma(a, (v2f){f1[mm], f1[mm]}, S01[1]);
      S23[1] = __builtin_elementwise_fma(b, (v2f){f1[mm], f1[mm]}, S23[1]);
      S01[2] = __builtin_elementwise_fma(a, (v2f){f2[mm], f2[mm]}, S01[2]);
      S23[2] = __builtin_elementwise_fma(b, (v2f){f2[mm], f2[mm]}, S23[2]);
    }
    #pragma unroll
    for (int k = 0; k < 3; ++k){
      v2f hp0 = C01[k] + S01[k], hp1 = C23[k] + S23[k];
      v2f hm0 = C01[k] - S01[k], hm1 = C23[k] - S23[k];
      float sp = (fexp2(hp0.x) + fexp2(hp0.y)) + (fexp2(hp1.x) + fexp2(hp1.y));
      float sm = (fexp2(hm0.x) + fexp2(hm0.y)) + (fexp2(hm1.x) + fexp2(hm1.y));
      float hvp = flog2(sp), hvm = flog2(sm);
      smx[k] = fmaxf(smx[k], fmaxf(hvp, hvm));
      if (k < 2 || tail_ok){
        int p = lane + 64*k;
        if (HALF){
          hbuf[rowoff + p] = (_Float16)hvp;
          if (p) hbuf[rowoff + 359 - p] = (_Float16)hvm;
        } else {
          fbuf[rowoff + p] = hvp;
          if (p) fbuf[rowoff + 359 - p] = hvm;
        }
      }
    }
    rowoff += RES_A;
  }
  float smax = fmaxf(fmaxf(smx[0], smx[1]), smx[2]);
  #pragma unroll
  for (int off = 32; off > 0; off >>= 1)
    smax = fmaxf(smax, __shfl_xor(smax, off, 64));
  if (lane == 0) wred[wave] = smax;
  __syncthreads();
  if (tid == 0){
    float m = fmaxf(fmaxf(wred[0], wred[1]), fmaxf(wred[2], wred[3]));
    atomicMax(gmax + g, enc_f(m));
  }
}

template<int HALF>
__global__ __launch_bounds__(256) void fixup_kernel(const _Float16* __restrict__ hbuf,
                                                    float* __restrict__ logits,
                                                    const unsigned* __restrict__ gmax){
  const float LN2 = 0.69314718055994531f;
  if (HALF){
    const int total8 = TOT_L/8;
    const uint4* hv = reinterpret_cast<const uint4*>(hbuf);
    float4* l4 = reinterpret_cast<float4*>(logits);
    int stride = gridDim.x * 256;
    for (int i = blockIdx.x * 256 + threadIdx.x; i < total8; i += stride){
      int g = (int)(((unsigned)i) / (PER_G/8));
      float nsub = -dec_f(gmax[g]) * LN2;
      union { uint4 u; _Float16 h[8]; } un;
      un.u = hv[i];
      float4 o0, o1;
      o0.x = fmaf((float)un.h[0], LN2, nsub);
      o0.y = fmaf((float)un.h[1], LN2, nsub);
      o0.z = fmaf((float)un.h[2], LN2, nsub);
      o0.w = fmaf((float)un.h[3], LN2, nsub);
      o1.x = fmaf((float)un.h[4], LN2, nsub);
      o1.y = fmaf((float)un.h[5], LN2, nsub);
      o1.z = fmaf((float)un.h[6], LN2, nsub);
      o1.w = fmaf((float)un.h[7], LN2, nsub);
      l4[2*i]   = o0;
      l4[2*i+1] = o1;
    }
  } else {
    const int total4 = TOT_L/4;
    float4* l4 = reinterpret_cast<float4*>(logits);
    int stride = gridDim.x * 256;
    for (int i = blockIdx.x * 256 + threadIdx.x; i < total4; i += stride){
      int g = (int)(((unsigned)i) / (PER_G/4));
      float nsub = -dec_f(gmax[g]) * LN2;
      float4 v = l4[i];
      v.x = fmaf(v.x, LN2, nsub); v.y = fmaf(v.y, LN2, nsub);
      v.z = fmaf(v.z, LN2, nsub); v.w = fmaf(v.w, LN2, nsub);
      l4[i] = v;
    }
  }
}

extern "C" void kernel_launch(void* const* d_in, const int* in_sizes, int n_in,
                              void* d_out, int out_size, void* d_ws, size_t ws_size,
                              hipStream_t stream){
  const float* focus = (const float*)d_in[0];
  const float* embt  = (const float*)d_in[1];
  const float* W     = (const float*)d_in[2];
  const int*   tspec = (const int*)d_in[3];
  float* out = (float*)d_out;
  float* ws  = (float*)d_ws;
  unsigned* gmax = (unsigned*)d_ws;          // 32 u32
  float* PYs  = ws + 32;                     // [180][36]
  float* Ftab = ws + 32 + RES_B*36;          // [359][12]
  _Float16* hbuf = (_Float16*)(ws + 16384);  // 83 MB
  float* tmpg = ws + 16384 + TOT_L/2;        // [TMP_T][12][4] = 22.1 MB

  const size_t need = 65536 + (size_t)TOT_L*2 + (size_t)TMP_T*48*4;
  const bool pre = (ws_size >= need);

  hipMemsetAsync(d_ws, 0, 128, stream);
  fused_prep_kernel<<<361, 256, 0, stream>>>(focus, embt, W, tspec, out, PYs, Ftab);
  float* logits = out + COEFF_N;
  if (pre){
    tmp_kernel<<<(TMP_T*11)/256, 256, 0, stream>>>(out, PYs, tmpg);
    compute_kernel<1,1><<<G_N*RADII*NCHUNK, 256, 0, stream>>>(out, PYs, Ftab, tmpg, hbuf, logits, gmax);
    fixup_kernel<1><<<2048, 256, 0, stream>>>(hbuf, logits, gmax);
  } else {
    compute_kernel<0,0><<<G_N*RADII*NCHUNK, 256, 0, stream>>>(out, PYs, Ftab, tmpg, hbuf, logits, gmax);
    fixup_kernel<0><<<2048, 256, 0, stream>>>(hbuf, logits, gmax);
  }
}